// Round 3
// baseline (1436.784 us; speedup 1.0000x reference)
//
#include <hip/hip_runtime.h>
#include <stdint.h>

typedef __bf16 bf8_t __attribute__((ext_vector_type(8)));
typedef float f32x4 __attribute__((ext_vector_type(4)));

#define EPSV 1e-5f
#define LSTR 40   // LDS row stride (elements), padded to break conflicts

__device__ __forceinline__ float b2f(unsigned short u) {
  union { uint32_t i; float f; } v; v.i = ((uint32_t)u) << 16; return v.f;
}
__device__ __forceinline__ unsigned short f2b(float f) {
  union { float f; uint32_t i; } v; v.f = f;
  uint32_t x = v.i;
  return (unsigned short)((x + 0x7fffu + ((x >> 16) & 1u)) >> 16);  // RNE
}

// ---------------------------------------------------------------- fp32 -> bf16 convert
__global__ __launch_bounds__(256) void cvt_f2b(const float* __restrict__ in,
                                               unsigned short* __restrict__ out, int n) {
  int gid = blockIdx.x * 256 + threadIdx.x;
  if (gid < n) out[gid] = f2b(in[gid]);
}

// ---------------------------------------------------------------- stage 1: y1 = xyz @ W1^T (K=3), all fp32
__global__ __launch_bounds__(256) void stage1(const float* __restrict__ xyz,
                                              const float* __restrict__ W1,
                                              float* __restrict__ y1) {
  int gid = blockIdx.x * 256 + threadIdx.x;   // 8192*64
  int r = gid >> 6, o = gid & 63;
  float x0 = xyz[r*3+0], x1 = xyz[r*3+1], x2 = xyz[r*3+2];
  float w0 = W1[o*3+0], w1 = W1[o*3+1], w2 = W1[o*3+2];
  y1[gid] = x0*w0 + x1*w1 + x2*w2;
}

// ---------------------------------------------------------------- per-channel sum/sumsq (bf16 or fp32 input)
__global__ __launch_bounds__(256) void colstats(const unsigned short* __restrict__ y16,
                                                const float* __restrict__ y32, int O,
                                                float* __restrict__ acc) {
  int col = blockIdx.x * 64 + (threadIdx.x & 63);
  long rbase = (long)blockIdx.y * 1024 + (threadIdx.x >> 6);
  float s = 0.f, s2 = 0.f;
  for (int i = 0; i < 256; ++i) {
    long idx = (rbase + (long)i*4) * O + col;
    float v = y32 ? y32[idx] : b2f(y16[idx]);
    s += v; s2 += v*v;
  }
  __shared__ float red[512];
  red[threadIdx.x] = s; red[256 + threadIdx.x] = s2;
  __syncthreads();
  if (threadIdx.x < 64) {
    float S = 0.f, S2 = 0.f;
    for (int j = 0; j < 4; ++j) { S += red[threadIdx.x + 64*j]; S2 += red[256 + threadIdx.x + 64*j]; }
    atomicAdd(&acc[col], S);
    atomicAdd(&acc[O + col], S2);
  }
}

// ---------------------------------------------------------------- BN finalize: a = g*rsqrt(v+eps), cc = b - m*a
__global__ void finalize_stats(const float* __restrict__ acc, const float* __restrict__ g,
                               const float* __restrict__ b, int O, float invCount,
                               float* __restrict__ a, float* __restrict__ cc) {
  int c = blockIdx.x * 256 + threadIdx.x;
  if (c >= O) return;
  float m = acc[c] * invCount;
  float v = fmaxf(acc[O + c] * invCount - m*m, 0.f);
  float rs = rsqrtf(v + EPSV);
  float A = g[c] * rs;
  a[c] = A; cc[c] = b[c] - m * A;
}

// ---------------------------------------------------------------- KNN top-8 (fp32, register insertion sort)
__global__ __launch_bounds__(256) void knn_kernel(const float* __restrict__ xyz,
                                                  int* __restrict__ flat_src) {
  __shared__ float px[1024], py[1024], pz[1024], sq[1024];
  int b = blockIdx.x;
  for (int i = threadIdx.x; i < 1024; i += 256) {
    float x = xyz[(b*1024 + i)*3 + 0];
    float y = xyz[(b*1024 + i)*3 + 1];
    float z = xyz[(b*1024 + i)*3 + 2];
    px[i] = x; py[i] = y; pz[i] = z; sq[i] = x*x + y*y + z*z;
  }
  __syncthreads();
  int q = blockIdx.y * 256 + threadIdx.x;
  float qx = px[q], qy = py[q], qz = pz[q], qs = sq[q];
  float bd[8]; int bi[8];
  #pragma unroll
  for (int j = 0; j < 8; ++j) { bd[j] = 3.4e38f; bi[j] = 0; }
  for (int m = 0; m < 1024; ++m) {
    float dot = qx*px[m] + qy*py[m] + qz*pz[m];
    float d2 = qs + sq[m] - 2.f*dot;      // exact reference formula (tie behavior)
    if (d2 < bd[7]) {
      bd[7] = d2; bi[7] = m;
      #pragma unroll
      for (int j = 7; j > 0; --j) {
        if (bd[j] < bd[j-1]) {
          float td = bd[j]; bd[j] = bd[j-1]; bd[j-1] = td;
          int ti = bi[j]; bi[j] = bi[j-1]; bi[j-1] = ti;
        }
      }
    }
  }
  #pragma unroll
  for (int j = 0; j < 8; ++j) flat_src[(b*1024 + q)*8 + j] = b*1024 + bi[j];
}

// ---------------------------------------------------------------- weight diff: WD = (W_right - W_left), fp32 -> bf16
__global__ __launch_bounds__(256) void wdiff(const float* __restrict__ W, int H,
                                             unsigned short* __restrict__ WD) {
  int gid = blockIdx.x * 256 + threadIdx.x;   // O*H
  int o = gid / H, h = gid - o*H;
  WD[gid] = f2b(W[o*2*H + H + h] - W[o*2*H + h]);
}

// ---------------------------------------------------------------- the MFMA GEMM (128x128 tile)
union GemmSmem {
  struct { unsigned short A[128*LSTR]; unsigned short W[128*LSTR]; } st;  // 20 KB
  struct { float acc[128*33]; float red[512]; } epi;                      // 18.9 KB
};

__global__ __launch_bounds__(256) void gemm_kernel(
    const unsigned short* __restrict__ A16, const float* __restrict__ A32, long strideA,
    const float* __restrict__ affA, const float* __restrict__ affC,   // per-k affine+relu on load, or NULL
    const int* __restrict__ rowmap,                                   // gather map, or NULL
    const unsigned short* __restrict__ W, int strideW,
    int K, int O,
    const float* __restrict__ addC,                                   // fp32 [rows/8][O] added pre-store, or NULL
    unsigned short* __restrict__ outB,                                // bf16 output, or NULL
    float* __restrict__ outF,                                         // fp32 output, or NULL
    float* __restrict__ ymax, float* __restrict__ ymin,               // fp32 maxmin path when non-NULL
    float* __restrict__ statsAcc)                                     // [2*O] sums (maxmin path)
{
  __shared__ GemmSmem sm;

  const int t = threadIdx.x;
  const int wave = t >> 6, lane = t & 63, quad = lane >> 4, lr = lane & 15;
  const int wr0 = (wave >> 1) * 64, wc0 = (wave & 1) * 64;
  const long rowBase = (long)blockIdx.x * 128;
  const int colBase = blockIdx.y * 128;

  const int sRow = t >> 2;          // 0..63 (two rows per thread: sRow, sRow+64)
  const int sK = (t & 3) * 8;       // 0,8,16,24

  long gg0 = rowBase + sRow;
  long gg1 = rowBase + sRow + 64;
  const long src0 = rowmap ? (long)rowmap[gg0] : gg0;
  const long src1 = rowmap ? (long)rowmap[gg1] : gg1;
  const long off0 = src0 * strideA + sK;
  const long off1 = src1 * strideA + sK;
  const unsigned short* wRow0 = W + (long)(colBase + sRow) * strideW + sK;
  const unsigned short* wRow1 = W + (long)(colBase + sRow + 64) * strideW + sK;

  f32x4 acc[4][4];
  #pragma unroll
  for (int i = 0; i < 4; ++i)
    #pragma unroll
    for (int j = 0; j < 4; ++j)
      acc[i][j] = (f32x4){0.f, 0.f, 0.f, 0.f};

  for (int k0 = 0; k0 < K; k0 += 32) {
    uint4 va0, va1;
    uint4 vw0 = *(const uint4*)(wRow0 + k0);
    uint4 vw1 = *(const uint4*)(wRow1 + k0);
    if (A32) {
      const float* p0 = A32 + off0 + k0;
      const float* p1 = A32 + off1 + k0;
      float4 f0a = ((const float4*)p0)[0], f0b = ((const float4*)p0)[1];
      float4 f1a = ((const float4*)p1)[0], f1b = ((const float4*)p1)[1];
      float x0[8] = {f0a.x, f0a.y, f0a.z, f0a.w, f0b.x, f0b.y, f0b.z, f0b.w};
      float x1[8] = {f1a.x, f1a.y, f1a.z, f1a.w, f1b.x, f1b.y, f1b.z, f1b.w};
      unsigned short* u0 = (unsigned short*)&va0;
      unsigned short* u1 = (unsigned short*)&va1;
      if (affA) {
        const float4* pa = (const float4*)(affA + k0 + sK);
        const float4* pc = (const float4*)(affC + k0 + sK);
        float4 fa0 = pa[0], fa1 = pa[1], fc0 = pc[0], fc1 = pc[1];
        float av[8] = {fa0.x, fa0.y, fa0.z, fa0.w, fa1.x, fa1.y, fa1.z, fa1.w};
        float cv[8] = {fc0.x, fc0.y, fc0.z, fc0.w, fc1.x, fc1.y, fc1.z, fc1.w};
        #pragma unroll
        for (int i = 0; i < 8; ++i) {
          u0[i] = f2b(fmaxf(av[i]*x0[i] + cv[i], 0.f));   // single rounding: fp32 -> bf16
          u1[i] = f2b(fmaxf(av[i]*x1[i] + cv[i], 0.f));
        }
      } else {
        #pragma unroll
        for (int i = 0; i < 8; ++i) { u0[i] = f2b(x0[i]); u1[i] = f2b(x1[i]); }
      }
    } else {
      va0 = *(const uint4*)(A16 + off0 + k0);
      va1 = *(const uint4*)(A16 + off1 + k0);
      if (affA) {
        const float4* pa = (const float4*)(affA + k0 + sK);
        const float4* pc = (const float4*)(affC + k0 + sK);
        float4 fa0 = pa[0], fa1 = pa[1], fc0 = pc[0], fc1 = pc[1];
        float av[8] = {fa0.x, fa0.y, fa0.z, fa0.w, fa1.x, fa1.y, fa1.z, fa1.w};
        float cv[8] = {fc0.x, fc0.y, fc0.z, fc0.w, fc1.x, fc1.y, fc1.z, fc1.w};
        unsigned short* u0 = (unsigned short*)&va0;
        unsigned short* u1 = (unsigned short*)&va1;
        #pragma unroll
        for (int i = 0; i < 8; ++i) {
          u0[i] = f2b(fmaxf(av[i]*b2f(u0[i]) + cv[i], 0.f));
          u1[i] = f2b(fmaxf(av[i]*b2f(u1[i]) + cv[i], 0.f));
        }
      }
    }
    __syncthreads();
    *(uint4*)&sm.st.A[sRow*LSTR + sK]        = va0;
    *(uint4*)&sm.st.A[(sRow + 64)*LSTR + sK] = va1;
    *(uint4*)&sm.st.W[sRow*LSTR + sK]        = vw0;
    *(uint4*)&sm.st.W[(sRow + 64)*LSTR + sK] = vw1;
    __syncthreads();
    bf8_t af[4], bfr[4];
    #pragma unroll
    for (int s = 0; s < 4; ++s) {
      af[s]  = *(const bf8_t*)&sm.st.A[(wr0 + s*16 + lr)*LSTR + quad*8];
      bfr[s] = *(const bf8_t*)&sm.st.W[(wc0 + s*16 + lr)*LSTR + quad*8];
    }
    #pragma unroll
    for (int sr = 0; sr < 4; ++sr)
      #pragma unroll
      for (int sc = 0; sc < 4; ++sc)
        acc[sr][sc] = __builtin_amdgcn_mfma_f32_16x16x32_bf16(af[sr], bfr[sc], acc[sr][sc], 0, 0, 0);
  }

  if (!ymax) {
    // plain epilogue: optional center-add, write bf16 or fp32
    #pragma unroll
    for (int sr = 0; sr < 4; ++sr) {
      #pragma unroll
      for (int sc = 0; sc < 4; ++sc) {
        int col = colBase + wc0 + sc*16 + lr;
        #pragma unroll
        for (int r = 0; r < 4; ++r) {
          long row = rowBase + wr0 + sr*16 + quad*4 + r;
          float v = acc[sr][sc][r];
          if (addC) v += addC[(row >> 3) * (long)O + col];
          if (outF) outF[row * (long)O + col] = v;
          else      outB[row * (long)O + col] = f2b(v);
        }
      }
    }
  } else {
    // maxmin epilogue: per 8-row group max/min (fp32) + per-channel stats
    const int tc = t & 31, tg8 = t >> 5;
    for (int chunk = 0; chunk < 4; ++chunk) {
      __syncthreads();
      if ((wave & 1) == (chunk >> 1)) {
        int scStart = (chunk & 1) * 2;
        #pragma unroll
        for (int s2i = 0; s2i < 2; ++s2i) {
          int sc = scStart + s2i;
          int colLocal = s2i*16 + lr;
          #pragma unroll
          for (int sr = 0; sr < 4; ++sr) {
            int rb = wr0 + sr*16 + quad*4;
            #pragma unroll
            for (int r = 0; r < 4; ++r)
              sm.epi.acc[(rb + r)*33 + colLocal] = acc[sr][sc][r];
          }
        }
      }
      __syncthreads();
      float s = 0.f, s2v = 0.f;
      #pragma unroll
      for (int gi = 0; gi < 2; ++gi) {
        int g = tg8*2 + gi;
        float mx = -3.4e38f, mn = 3.4e38f;
        #pragma unroll
        for (int i = 0; i < 8; ++i) {
          float v = sm.epi.acc[(g*8 + i)*33 + tc];
          mx = fmaxf(mx, v); mn = fminf(mn, v); s += v; s2v += v*v;
        }
        long orow = (long)blockIdx.x*16 + g;
        int col = colBase + chunk*32 + tc;
        ymax[orow * O + col] = mx;
        ymin[orow * O + col] = mn;
      }
      sm.epi.red[t] = s; sm.epi.red[256 + t] = s2v;
      __syncthreads();
      if (t < 32) {
        float S = 0.f, S2 = 0.f;
        #pragma unroll
        for (int j = 0; j < 8; ++j) { S += sm.epi.red[t + 32*j]; S2 += sm.epi.red[256 + t + 32*j]; }
        int col = colBase + chunk*32 + t;
        atomicAdd(&statsAcc[col], S);
        atomicAdd(&statsAcc[O + col], S2);
      }
    }
  }
}

// ---------------------------------------------------------------- l0 from A2 maxmin (fp32 in, bf16 out)
__global__ __launch_bounds__(256) void to_l0(const float* __restrict__ ymax,
                                             const float* __restrict__ ymin,
                                             const float* __restrict__ a, const float* __restrict__ cc,
                                             unsigned short* __restrict__ l0) {
  int gid = blockIdx.x * 256 + threadIdx.x;   // 8192*512
  int c = gid & 511;
  float A = a[c];
  float v = (A >= 0.f) ? ymax[gid] : ymin[gid];
  l0[gid] = f2b(fmaxf(A*v + cc[c], 0.f));
}

// ---------------------------------------------------------------- final BN+ReLU + transpose, fp32 all the way
__global__ __launch_bounds__(256) void final_out(const float* __restrict__ ymax,
                                                 const float* __restrict__ ymin,
                                                 const float* __restrict__ a, const float* __restrict__ cc,
                                                 float* __restrict__ out) {
  __shared__ float tile[32][33];
  int b = blockIdx.x, ct = blockIdx.y * 32, nt = blockIdx.z * 32;
  int tc = threadIdx.x & 31, tr = threadIdx.x >> 5;
  #pragma unroll
  for (int i = 0; i < 4; ++i) {
    int n = nt + tr + i*8;
    int c = ct + tc;
    float A = a[c];
    long idx = ((long)(b*1024 + n))*1024 + c;
    float v = (A >= 0.f) ? ymax[idx] : ymin[idx];
    tile[tr + i*8][tc] = fmaxf(A*v + cc[c], 0.f);
  }
  __syncthreads();
  #pragma unroll
  for (int i = 0; i < 4; ++i) {
    int c = ct + tr + i*8;
    int n = nt + tc;
    out[((long)(b*1024 + c))*1024 + n] = tile[tc][tr + i*8];
  }
}

// ================================================================ host
extern "C" void kernel_launch(void* const* d_in, const int* in_sizes, int n_in,
                              void* d_out, int out_size, void* d_ws, size_t ws_size,
                              hipStream_t stream) {
  const float* xyz = (const float*)d_in[0];
  const float* W1  = (const float*)d_in[1];
  const float* g1  = (const float*)d_in[2];
  const float* b1  = (const float*)d_in[3];
  const float* W2  = (const float*)d_in[4];
  const float* g2  = (const float*)d_in[5];
  const float* b2  = (const float*)d_in[6];
  const float* WA1 = (const float*)d_in[7];
  const float* gA1 = (const float*)d_in[8];
  const float* bA1 = (const float*)d_in[9];
  const float* WA2 = (const float*)d_in[10];
  const float* gA2 = (const float*)d_in[11];
  const float* bA2 = (const float*)d_in[12];
  const float* WB1 = (const float*)d_in[13];
  const float* gB1 = (const float*)d_in[14];
  const float* bB1 = (const float*)d_in[15];
  const float* WB2 = (const float*)d_in[16];
  const float* gB2 = (const float*)d_in[17];
  const float* bB2 = (const float*)d_in[18];
  float* out = (float*)d_out;

  char* w = (char*)d_ws;
  const size_t MB = 1048576;

  // -------- small zone [0, 8 MB) --------
  size_t off = 0;
  auto nxt = [&](size_t bytes) { void* p = w + off; off = (off + bytes + 255) & ~(size_t)255; return p; };
  int*            flat_src = (int*)nxt(262144);
  unsigned short* W2b  = (unsigned short*)nxt(32768);
  unsigned short* WA1b = (unsigned short*)nxt(524288);
  unsigned short* WDA  = (unsigned short*)nxt(262144);
  unsigned short* WA2b = (unsigned short*)nxt(524288);
  unsigned short* WB1b = (unsigned short*)nxt(2097152);
  unsigned short* WDB  = (unsigned short*)nxt(1048576);
  unsigned short* WB2b = (unsigned short*)nxt(2097152);
  float* statsZone = (float*)nxt(27136);
  float* affZone   = (float*)nxt(27136);

  // -------- big zone (lifetime-aliased) --------
  // tier1 (ws >= 353 MB): fp32 yA1/yB1. tier2: bf16 yA1/yB1, fp32 everything else.
  const bool tier1 = (ws_size >= 353*MB);
  float*          y1f   = (float*)(w + 8*MB);            // [8,10)
  float*          y2f   = (float*)(w + 10*MB);           // [10,18)
  float*          yCA   = (float*)(w + 18*MB);           // [18,34)
  float*          ymaxA = (float*)(w + 8*MB);            // [8,24)   after y1/y2/yCA dead
  unsigned short* l0    = (unsigned short*)(w + 24*MB);  // [24,32)
  float*          yCB   = (float*)(w + 32*MB);           // [32,64)
  float*          ymaxB = (float*)(w + 8*MB);            // [8,40)   after l0/yCB dead
  // tier-dependent:
  float*          yA1f  = (float*)(w + 34*MB);           // [34,162) tier1
  unsigned short* yA1b  = (unsigned short*)(w + 34*MB);  // [34,98)  tier2
  float*          yminA = tier1 ? (float*)(w + 162*MB) : (float*)(w + 98*MB);
  float*          yB1f  = (float*)(w + 64*MB);           // [64,320) tier1
  unsigned short* yB1b  = (unsigned short*)(w + 64*MB);  // [64,192) tier2
  float*          yminB = tier1 ? (float*)(w + 320*MB) : (float*)(w + 192*MB);

  float* acc1  = statsZone;          // 2*64
  float* acc2  = statsZone + 128;    // 2*256
  float* accA1 = statsZone + 640;    // 2*512
  float* accA2 = statsZone + 1664;   // 2*512
  float* accB1 = statsZone + 2688;   // 2*1024
  float* accB2 = statsZone + 4736;   // 2*1024

  float* a1  = affZone;        float* cc1  = affZone + 64;
  float* a2  = affZone + 128;  float* cc2  = affZone + 384;
  float* aA1 = affZone + 640;  float* ccA1 = affZone + 1152;
  float* aA2 = affZone + 1664; float* ccA2 = affZone + 2176;
  float* aB1 = affZone + 2688; float* ccB1 = affZone + 3712;
  float* aB2 = affZone + 4736; float* ccB2 = affZone + 5760;

  hipMemsetAsync(statsZone, 0, 6784 * 4, stream);

  // weight conversions (fp32 -> bf16, single rounding) and diffs
  cvt_f2b<<<64, 256, 0, stream>>>(W2, W2b, 16384);
  cvt_f2b<<<1024, 256, 0, stream>>>(WA1, WA1b, 262144);
  cvt_f2b<<<1024, 256, 0, stream>>>(WA2, WA2b, 262144);
  cvt_f2b<<<4096, 256, 0, stream>>>(WB1, WB1b, 1048576);
  cvt_f2b<<<4096, 256, 0, stream>>>(WB2, WB2b, 1048576);
  wdiff<<<512, 256, 0, stream>>>(WA1, 256, WDA);
  wdiff<<<2048, 256, 0, stream>>>(WB1, 512, WDB);

  // stage 1 + BN (fp32)
  stage1<<<2048, 256, 0, stream>>>(xyz, W1, y1f);
  colstats<<<dim3(1, 8), 256, 0, stream>>>(nullptr, y1f, 64, acc1);
  finalize_stats<<<1, 256, 0, stream>>>(acc1, g1, b1, 64, 1.f/8192.f, a1, cc1);

  // stage 2 + BN (fp32 out)
  gemm_kernel<<<dim3(64, 2), 256, 0, stream>>>(nullptr, y1f, 64, a1, cc1, nullptr, W2b, 64, 64, 256,
                                               nullptr, nullptr, y2f, nullptr, nullptr, nullptr);
  colstats<<<dim3(4, 8), 256, 0, stream>>>(nullptr, y2f, 256, acc2);
  finalize_stats<<<1, 256, 0, stream>>>(acc2, g2, b2, 256, 1.f/8192.f, a2, cc2);

  // knn
  knn_kernel<<<dim3(8, 4), 256, 0, stream>>>(xyz, flat_src);

  // stage A1: center GEMM then gather GEMM
  gemm_kernel<<<dim3(64, 4), 256, 0, stream>>>(nullptr, y2f, 256, a2, cc2, nullptr, WDA, 256, 256, 512,
                                               nullptr, nullptr, yCA, nullptr, nullptr, nullptr);
  if (tier1) {
    gemm_kernel<<<dim3(512, 4), 256, 0, stream>>>(nullptr, y2f, 256, a2, cc2, flat_src, WA1b, 512, 256, 512,
                                                  yCA, nullptr, yA1f, nullptr, nullptr, nullptr);
    colstats<<<dim3(8, 64), 256, 0, stream>>>(nullptr, yA1f, 512, accA1);
  } else {
    gemm_kernel<<<dim3(512, 4), 256, 0, stream>>>(nullptr, y2f, 256, a2, cc2, flat_src, WA1b, 512, 256, 512,
                                                  yCA, yA1b, nullptr, nullptr, nullptr, nullptr);
    colstats<<<dim3(8, 64), 256, 0, stream>>>(yA1b, nullptr, 512, accA1);
  }
  finalize_stats<<<2, 256, 0, stream>>>(accA1, gA1, bA1, 512, 1.f/65536.f, aA1, ccA1);

  // stage A2: maxmin GEMM (fp32 maxmin out)
  if (tier1)
    gemm_kernel<<<dim3(512, 4), 256, 0, stream>>>(nullptr, yA1f, 512, aA1, ccA1, nullptr, WA2b, 512, 512, 512,
                                                  nullptr, nullptr, nullptr, ymaxA, yminA, accA2);
  else
    gemm_kernel<<<dim3(512, 4), 256, 0, stream>>>(yA1b, nullptr, 512, aA1, ccA1, nullptr, WA2b, 512, 512, 512,
                                                  nullptr, nullptr, nullptr, ymaxA, yminA, accA2);
  finalize_stats<<<2, 256, 0, stream>>>(accA2, gA2, bA2, 512, 1.f/65536.f, aA2, ccA2);
  to_l0<<<16384, 256, 0, stream>>>(ymaxA, yminA, aA2, ccA2, l0);

  // stage B1
  gemm_kernel<<<dim3(64, 8), 256, 0, stream>>>(l0, nullptr, 512, nullptr, nullptr, nullptr, WDB, 512, 512, 1024,
                                               nullptr, nullptr, yCB, nullptr, nullptr, nullptr);
  if (tier1) {
    gemm_kernel<<<dim3(512, 8), 256, 0, stream>>>(l0, nullptr, 512, nullptr, nullptr, flat_src, WB1b, 1024, 512, 1024,
                                                  yCB, nullptr, yB1f, nullptr, nullptr, nullptr);
    colstats<<<dim3(16, 64), 256, 0, stream>>>(nullptr, yB1f, 1024, accB1);
  } else {
    gemm_kernel<<<dim3(512, 8), 256, 0, stream>>>(l0, nullptr, 512, nullptr, nullptr, flat_src, WB1b, 1024, 512, 1024,
                                                  yCB, yB1b, nullptr, nullptr, nullptr, nullptr);
    colstats<<<dim3(16, 64), 256, 0, stream>>>(yB1b, nullptr, 1024, accB1);
  }
  finalize_stats<<<4, 256, 0, stream>>>(accB1, gB1, bB1, 1024, 1.f/65536.f, aB1, ccB1);

  // stage B2: maxmin GEMM (fp32 maxmin out)
  if (tier1)
    gemm_kernel<<<dim3(512, 8), 256, 0, stream>>>(nullptr, yB1f, 1024, aB1, ccB1, nullptr, WB2b, 1024, 1024, 1024,
                                                  nullptr, nullptr, nullptr, ymaxB, yminB, accB2);
  else
    gemm_kernel<<<dim3(512, 8), 256, 0, stream>>>(yB1b, nullptr, 1024, aB1, ccB1, nullptr, WB2b, 1024, 1024, 1024,
                                                  nullptr, nullptr, nullptr, ymaxB, yminB, accB2);
  finalize_stats<<<4, 256, 0, stream>>>(accB2, gB2, bB2, 1024, 1.f/65536.f, aB2, ccB2);

  // final: BN+ReLU from fp32 maxmin, transposed fp32 write
  final_out<<<dim3(8, 32, 32), 256, 0, stream>>>(ymaxB, yminB, aB2, ccB2, out);
}